// Round 18
// baseline (356.679 us; speedup 1.0000x reference)
//
#include <hip/hip_runtime.h>
#include <hip/hip_bf16.h>

#define NTRAIN 100000
#define NBIT   64
#define NCLASS 100
#define NBATCH 128
#define NW     1563   /* ceil(100000/64) */
#define NWP    1568   /* padded stride   */
#define NP1    100001.0f
#define ETA_MU 55.0f

#define NBLK   391    /* ceil(100000/256) */
#define NLIKB  1568   /* 49 chunks x 32 (8 XCD-lanes x 4 b-quarters) */
#define CCH    16     /* words per k_bbt4 chunk */
#define NCHUNK 98     /* 98*16 = 1568 >= NW */
#define SCAP   4096   /* slow-column list capacity */
#define SLACK  2e-5f  /* fp-rounding guard on the |p| > rowabs test */

typedef unsigned long long u64;
typedef unsigned int u32;

// ---------------- workspace layout (bytes) ----------------
#define OFF_BMASK   0u                       /* u64[100000]        800000 */
#define OFF_CMASK   800000u                  /* u64[100][1568]    1254400 */
#define OFF_LABELY  2054400u                 /* int[100000]        400000 */
#define OFF_OVR     2454400u                 /* int[100000]        400000 */
#define OFF_YLAB    2854400u                 /* int[128]              512 */
#define OFF_CCOUNT  2854912u                 /* int[100]              512 */
#define OFF_AF      2855424u                 /* f32[4096]           16384 */
#define OFF_RHS     2871808u                 /* f32[100][64]        25600 */
#define OFF_W       2897408u                 /* f32[64][100]        25600 */
#define OFF_WT      2923008u                 /* f32[100][64]        25600 */
#define OFF_G       2948608u                 /* f32[64][64]         16384 */
#define OFF_PA      2967040u                 /* int[98][4096]; reused as k_lik partials f32[1568] */
#define OFF_PB      4572672u                 /* int[98][6400]     2508800 */
#define OFF_ROWABS  7081472u                 /* f32[64]               256 */
#define OFF_SCNT    7081728u                 /* int[1] (+pad)         256 */
#define OFF_SLIST   7081984u                 /* int[4096]           16384 */
#define OFF_SOLD    7098368u                 /* u64[4096]           32768 */
/* total ~7.13 MB */

__device__ __forceinline__ float blk_reduce_sum(float v, float* sbuf) {
    int tid = threadIdx.x;
    for (int off = 32; off > 0; off >>= 1) v += __shfl_down(v, off, 64);
    __syncthreads();
    if ((tid & 63) == 0) sbuf[tid >> 6] = v;
    __syncthreads();
    float t = 0.f;
    if (tid == 0) {
        int nw = (int)(blockDim.x >> 6);
        for (int q = 0; q < nw; ++q) t += sbuf[q];
    }
    return t;   // valid on tid 0 only
}

// batch labels + override table (runs FIRST); also zeroes ccount for k_prep
__global__ void k_scatter(const float* __restrict__ y, const int* __restrict__ ind,
                          int* __restrict__ ovr, int* __restrict__ ylab,
                          int* __restrict__ ccount) {
    __shared__ int cls[NBATCH], idx[NBATCH];
    int k = threadIdx.x;
    if (k < NCLASS) ccount[k] = 0;
    if (k < NBATCH) {
        int c = 0;
        for (int r = 0; r < NCLASS; ++r)
            if (y[k * NCLASS + r] > 0.5f) c = r;
        cls[k] = c; idx[k] = ind[k]; ylab[k] = c;
    }
    __syncthreads();
    if (k == 0) {
        for (int q = 0; q < NBATCH; ++q) ovr[idx[q]] = q + 1;
    }
}

// fused: label per column (Y or override), B sign-mask, cmask via wave ballots,
// class counts via LDS histogram + deterministic integer atomics
__global__ __launch_bounds__(256) void k_prep(const float* __restrict__ Y,
                                              const float* __restrict__ B,
                                              const int* __restrict__ ovr,
                                              const int* __restrict__ ylab,
                                              int* __restrict__ labelY,
                                              u64* __restrict__ Bmask,
                                              u64* __restrict__ cmask,
                                              int* __restrict__ ccount) {
    __shared__ int hist[NCLASS];
    int tid = threadIdx.x, lane = tid & 63, wid = tid >> 6;
    if (tid < NCLASS) hist[tid] = 0;
    __syncthreads();
    int w = blockIdx.x * 4 + wid;
    int j = w * 64 + lane;
    int lab = -1;
    if (j < NTRAIN) {
        lab = 0;
        for (int r = 0; r < NCLASS; ++r)
            if (Y[r * NTRAIN + j] > 0.5f) lab = r;
        int ov = ovr[j];
        if (ov) lab = ylab[ov - 1];
        labelY[j] = lab;
        u64 m = 0ull;
        #pragma unroll
        for (int i = 0; i < NBIT; ++i)
            if (B[i * NTRAIN + j] > 0.0f) m |= (1ull << i);
        Bmask[j] = m;
        atomicAdd(&hist[lab], 1);
    }
    u64 keep0 = 0ull, keep1 = 0ull;
    for (int c = 0; c < NCLASS; ++c) {
        u64 bal = __ballot(lab == c);
        if (lane == c)      keep0 = bal;
        if (lane == c - 64) keep1 = bal;
    }
    if (w < NW) {
        cmask[(size_t)lane * NWP + w] = keep0;
        if (lane < NCLASS - 64) cmask[(size_t)(lane + 64) * NWP + w] = keep1;
    }
    __syncthreads();
    if (tid < NCLASS && hist[tid]) atomicAdd(&ccount[tid], hist[tid]);
}

// fused ballot-transpose + chunked BB^T / BY^T -> PLAIN partial stores
__global__ __launch_bounds__(256) void k_bbt4(const u64* __restrict__ Bmask,
                                              const u64* __restrict__ cmask,
                                              int* __restrict__ pA,
                                              int* __restrict__ pB) {
    __shared__ u64 Lp[64 * 17];
    __shared__ u64 Lc[100 * 17];
    int tid = threadIdx.x, lane = tid & 63, wid = tid >> 6;
    int w0 = blockIdx.x * CCH;
    for (int idx = tid; idx < 100 * CCH; idx += 256) {
        int r = idx >> 4, w = idx & 15;
        int gw = w0 + w;
        Lc[r * 17 + w] = (gw < NW) ? cmask[(size_t)r * NWP + gw] : 0ull;
    }
    for (int rr = 0; rr < 4; ++rr) {
        int w = wid * 4 + rr;
        int j = (w0 + w) * 64 + lane;
        u64 m = (j < NTRAIN) ? Bmask[j] : 0ull;
        u64 acc = 0ull;
        #pragma unroll
        for (int i = 0; i < 64; ++i) {
            u64 bal = __ballot((m >> i) & 1ull);
            if (lane == i) acc = bal;
        }
        Lp[lane * 17 + w] = acc;
    }
    __syncthreads();
    int k = lane, grp = wid;
    int cntA[16], cntB[25];
    #pragma unroll
    for (int i = 0; i < 16; ++i) cntA[i] = 0;
    #pragma unroll
    for (int i = 0; i < 25; ++i) cntB[i] = 0;
    for (int w = 0; w < CCH; ++w) {
        u64 pkw = Lp[k * 17 + w];
        #pragma unroll
        for (int li = 0; li < 16; ++li)
            cntA[li] += __popcll(pkw ^ Lp[(grp + 4 * li) * 17 + w]);
        #pragma unroll
        for (int ci = 0; ci < 25; ++ci)
            cntB[ci] += __popcll(pkw & Lc[(grp * 25 + ci) * 17 + w]);
    }
    size_t bA = (size_t)blockIdx.x * 4096;
    size_t bB = (size_t)blockIdx.x * 6400;
    #pragma unroll
    for (int li = 0; li < 16; ++li)
        pA[bA + (size_t)(grp + 4 * li) * 64 + k] = cntA[li];
    #pragma unroll
    for (int ci = 0; ci < 25; ++ci)
        pB[bB + (size_t)(grp * 25 + ci) * 64 + k] = cntB[ci];
}

// reduce partials -> A_f (scaled, zero-diag) and RHS_f[c*64+k]
__global__ __launch_bounds__(256) void k_reduce(const int* __restrict__ pA,
                                                const int* __restrict__ pB,
                                                const int* __restrict__ ccount,
                                                float* __restrict__ A_f,
                                                float* __restrict__ RHS_f) {
    int tid = threadIdx.x, blk = blockIdx.x;
    if (blk < 16) {
        int e = blk * 256 + tid;
        int s = 0;
        for (int ch = 0; ch < NCHUNK; ++ch) s += pA[(size_t)ch * 4096 + e];
        A_f[e] = ((e >> 6) == (e & 63)) ? 0.0f
                                        : (float)(NTRAIN - 2 * s) * (1.0f / NP1);
    } else {
        int e = (blk - 16) * 256 + tid;
        int s = 0;
        for (int ch = 0; ch < NCHUNK; ++ch) s += pB[(size_t)ch * 6400 + e];
        RHS_f[e] = (float)(2 * s - ccount[e >> 6]);
    }
}

// per-column Neumann solve: x <- v - A x (4 matvecs, ||A||~0.05)
__global__ __launch_bounds__(256) void k_wsolve(const float* __restrict__ A_f,
                                                const float* __restrict__ RHS_f,
                                                float* __restrict__ W_g,
                                                float* __restrict__ WT_g) {
    __shared__ float As[64 * 65];
    __shared__ float xb[4][64];
    int tid = threadIdx.x, lane = tid & 63, wid = tid >> 6;
    for (int e = tid; e < 4096; e += 256)
        As[(e >> 6) * 65 + (e & 63)] = A_f[e];
    int c = blockIdx.x * 4 + wid;
    float v = RHS_f[c * 64 + lane];
    float x = v;
    __syncthreads();
    for (int it = 0; it < 4; ++it) {
        xb[wid][lane] = x;
        __syncthreads();
        const float* __restrict__ Ar = As + lane * 65;
        const float* __restrict__ xv = xb[wid];
        float a0 = 0, a1 = 0, a2 = 0, a3 = 0;
        #pragma unroll 8
        for (int k = 0; k < 64; k += 4) {
            a0 = fmaf(Ar[k],     xv[k],     a0);
            a1 = fmaf(Ar[k + 1], xv[k + 1], a1);
            a2 = fmaf(Ar[k + 2], xv[k + 2], a2);
            a3 = fmaf(Ar[k + 3], xv[k + 3], a3);
        }
        x = v - ((a0 + a1) + (a2 + a3));
        __syncthreads();
    }
    float w = x * (1.0f / NP1);
    W_g[lane * 100 + c] = w;
    WT_g[c * 64 + lane] = w;
}

// G = W W^T (zero diag) + rowabs_i = sum_k |G[i][k]| ; zeroes slow-count
__global__ __launch_bounds__(256) void k_gram(const float* __restrict__ WT,
                                              float* __restrict__ G_g,
                                              float* __restrict__ rowabs,
                                              int* __restrict__ scnt) {
    __shared__ float WTs[6400];
    int tid = threadIdx.x;
    for (int e = tid; e < 6400; e += 256) WTs[e] = WT[e];
    __syncthreads();
    int e = blockIdx.x * 256 + tid;
    int k = e >> 6, l = e & 63;
    float a0 = 0, a1 = 0;
    #pragma unroll 10
    for (int c = 0; c < 100; c += 2) {
        a0 = fmaf(WTs[c * 64 + k],       WTs[c * 64 + l],       a0);
        a1 = fmaf(WTs[(c + 1) * 64 + k], WTs[(c + 1) * 64 + l], a1);
    }
    float g = (k == l) ? 0.0f : (a0 + a1);
    G_g[e] = g;
    float v = fabsf(g);
    for (int off = 32; off > 0; off >>= 1) v += __shfl_down(v, off, 64);
    if ((tid & 63) == 0) rowabs[k] = v;
    if (blockIdx.x == 0 && tid == 0) *scnt = 0;
}

// ---------------- fast scan: B = sign(p), flag |p|<=rowabs columns ----------------
// EXACT for unflagged columns: |f_i| <= rowabs_i < |p_i| for every step of the
// reference's sequential scan => sign(p_i - f_i) == sign(p_i) regardless of state.
__global__ __launch_bounds__(256) void k_fast(const float* __restrict__ U,
                                              const float* __restrict__ u,
                                              const int* __restrict__ labelY,
                                              const int* __restrict__ ovr,
                                              const float* __restrict__ WT,
                                              const float* __restrict__ rowabs,
                                              u64* __restrict__ Bmask,
                                              int* __restrict__ slist,
                                              u64* __restrict__ sold,
                                              int* __restrict__ scnt) {
    __shared__ float WTs[100 * 65];   /* 65-pad: lane-varying c -> conflict-free */
    __shared__ float ra[64];
    int tid = threadIdx.x;
    for (int e = tid; e < 6400; e += 256)
        WTs[(e >> 6) * 65 + (e & 63)] = WT[e];
    if (tid < 64) ra[tid] = rowabs[tid] + SLACK;
    __syncthreads();
    int j = blockIdx.x * 256 + tid;
    if (j >= NTRAIN) return;
    int c = labelY[j], ov = ovr[j];
    const float* up; int str;
    if (ov) { up = u + (ov - 1) * NBIT; str = 1; }
    else    { up = U + j;               str = NTRAIN; }
    const float* wc = WTs + c * 65;
    u64 m = 0ull;
    int slow = 0;
    #pragma unroll
    for (int i = 0; i < NBIT; ++i) {
        float p = fmaf(ETA_MU, up[i * str], wc[i]);
        if (p > 0.0f) m |= (1ull << i);
        slow |= (fabsf(p) <= ra[i]);
    }
    if (slow) {
        int idx = atomicAdd(scnt, 1);
        if (idx < SCAP) { slist[idx] = j; sold[idx] = Bmask[j]; }
    }
    Bmask[j] = m;   // fallback for (impossible) list overflow; exact otherwise
}

// ---------------- wave-cooperative exact scan for flagged columns -------------
__global__ __launch_bounds__(1024) void k_slow(const int* __restrict__ slist,
                                               const u64* __restrict__ sold,
                                               const int* __restrict__ scnt,
                                               const int* __restrict__ labelY,
                                               const int* __restrict__ ovr,
                                               const float* __restrict__ G_g,
                                               const float* __restrict__ WT,
                                               const float* __restrict__ U,
                                               const float* __restrict__ u,
                                               u64* __restrict__ Bmask) {
    __shared__ float Gs[64 * 65];
    int tid = threadIdx.x, lane = tid & 63, wv = tid >> 6;   /* 16 waves */
    int n = *scnt; if (n > SCAP) n = SCAP;
    if (n == 0) return;
    for (int e = tid; e < 4096; e += 1024)
        Gs[(e >> 6) * 65 + (e & 63)] = G_g[e];
    __syncthreads();
    for (int idx = wv; idx < n; idx += 16) {
        int j = slist[idx];
        u64 m0 = sold[idx];
        int c = labelY[j], ov = ovr[j];
        float uval = ov ? u[(ov - 1) * NBIT + lane]
                        : U[(size_t)lane * NTRAIN + j];
        float p = fmaf(ETA_MU, uval, WT[c * 64 + lane]);
        float s = ((m0 >> lane) & 1ull) ? 1.0f : -1.0f;
        for (int i = 0; i < 64; ++i) {
            float t = Gs[i * 65 + lane] * s;   /* G[i,i]=0 -> self term drops */
            t += __shfl_xor(t, 1);  t += __shfl_xor(t, 2);
            t += __shfl_xor(t, 4);  t += __shfl_xor(t, 8);
            t += __shfl_xor(t, 16); t += __shfl_xor(t, 32);
            float nv = ((p - t) > 0.0f) ? 1.0f : -1.0f;
            s = (lane == i) ? nv : s;
        }
        u64 mo = __ballot(s > 0.0f);
        if (lane == 0) Bmask[j] = mo;
    }
}

// ---------------- likelihood: XCD-grouped, software-pipelined UC stream -------
// r17 lesson: each (bt,ch) step waited its 16 UC loads (~900cy first-touch)
// before 512cy of FMAs -> ~50% stall at 2 waves/SIMD. Restructure: ch-outer
// with ip[32] persistent, UC double-buffered (ping-pong names via fully
// unrolled ch -> compile-time selection, rule-#20 safe): next chunk's loads
// issue BEFORE the current 1024cy FMA block. UC loads also halve (bt-hoisted).
// Per-(bb,ch) arithmetic keeps r17's exact 4-accumulator grouping and ch-order
// -> bitwise-identical result.
__global__ __launch_bounds__(256) void k_lik(const float* __restrict__ U,
                                             const float* __restrict__ u,
                                             const int* __restrict__ labelY,
                                             const int* __restrict__ ovr,
                                             const int* __restrict__ ylab,
                                             float* __restrict__ partials) {
    __shared__ float sbuf[8];
    int bid = blockIdx.x;
    int x = bid & 7, q4 = (bid >> 3) & 3, chunk = bid >> 5;
    int jblk = chunk * 8 + x;
    int j = jblk * 256 + threadIdx.x;
    float acc = 0.0f;
    if (jblk < NBLK && j < NTRAIN) {
        int ov = ovr[j];
        const float* up; int ustr;
        if (ov) { up = u + (ov - 1) * NBIT; ustr = 1; }
        else    { up = U + j;               ustr = NTRAIN; }
        int cj = labelY[j];
        int b0 = q4 * 32;
        float ip[32];
        #pragma unroll
        for (int t = 0; t < 32; ++t) ip[t] = 0.0f;
        float UCa[16], UCb[16];
        #pragma unroll
        for (int t = 0; t < 16; ++t) UCa[t] = up[t * ustr];
        #pragma unroll
        for (int ch = 0; ch < 4; ++ch) {
            /* prefetch next chunk into the other buffer (issues early;
               wait lands before its first use in the NEXT ch copy) */
            if (ch < 3) {
                float* nxt = ((ch & 1) == 0) ? UCb : UCa;
                #pragma unroll
                for (int t = 0; t < 16; ++t)
                    nxt[t] = up[((ch + 1) * 16 + t) * ustr];
            }
            const float* UC = ((ch & 1) == 0) ? UCa : UCb;
            #pragma unroll
            for (int bb = 0; bb < 32; ++bb) {
                const float* __restrict__ ub = u + (b0 + bb) * NBIT + ch * 16;
                float s0 = 0.f, s1 = 0.f, s2 = 0.f, s3 = 0.f;
                #pragma unroll
                for (int t = 0; t < 16; t += 4) {
                    s0 = fmaf(ub[t],     UC[t],     s0);
                    s1 = fmaf(ub[t + 1], UC[t + 1], s1);
                    s2 = fmaf(ub[t + 2], UC[t + 2], s2);
                    s3 = fmaf(ub[t + 3], UC[t + 3], s3);
                }
                ip[bb] += (s0 + s1) + (s2 + s3);
            }
        }
        #pragma unroll
        for (int bb = 0; bb < 32; ++bb) {
            int b = b0 + bb;
            float ipv = 0.5f * ip[bb];
            float aip = fabsf(ipv);
            float t = __logf(1.0f + __expf(-aip)) + fmaxf(ipv, 0.0f);
            if (ylab[b] == cj) t -= ipv;
            acc += t;
        }
    }
    float tot = blk_reduce_sum(acc, sbuf);
    if (threadIdx.x == 0) partials[bid] = tot;
}

// fused: cl/reg losses + final combine
__global__ void k_clfin(const float* __restrict__ Wg,
                        const u64* __restrict__ Bmask,
                        const int* __restrict__ ind,
                        const float* __restrict__ y,
                        const float* __restrict__ partials,
                        float* __restrict__ out) {
    __shared__ float sbuf[8];
    __shared__ u64 mB[NBATCH];
    int tid = threadIdx.x;
    if (tid < NBATCH) mB[tid] = Bmask[ind[tid]];
    __syncthreads();
    float accCl = 0.f;
    for (int e = tid; e < NCLASS * NBATCH; e += 256) {
        int b = e & 127, c = e >> 7;
        u64 m = mB[b];
        float d0 = 0.f;
        #pragma unroll
        for (int i = 0; i < NBIT; ++i) {
            float w = Wg[i * NCLASS + c];
            d0 += ((m >> i) & 1ull) ? w : -w;
        }
        float diff = y[b * NCLASS + c] - d0;
        accCl = fmaf(diff, diff, accCl);
    }
    float accRg = 0.f;
    for (int e = tid; e < NBIT * NCLASS; e += 256) {
        float w = Wg[e];
        accRg = fmaf(w, w, accRg);
    }
    float a = 0.f;
    for (int i = tid; i < NLIKB; i += 256) a += partials[i];
    float clS  = blk_reduce_sum(accCl, sbuf);
    float rgS  = blk_reduce_sum(accRg, sbuf);
    float lik  = blk_reduce_sum(a, sbuf);
    if (tid == 0) {
        out[0] = lik * (1.0f / ((float)NBATCH * (float)NTRAIN))
               + clS * (1.0f / (float)(NCLASS * NBATCH))
               + rgS * (1.0f / (float)(NBIT * NCLASS));
    }
}

extern "C" void kernel_launch(void* const* d_in, const int* in_sizes, int n_in,
                              void* d_out, int out_size, void* d_ws, size_t ws_size,
                              hipStream_t stream) {
    const float* u   = (const float*)d_in[0];
    const float* y   = (const float*)d_in[1];
    const float* U   = (const float*)d_in[2];
    const float* B   = (const float*)d_in[3];
    const float* Y   = (const float*)d_in[4];
    const int*   ind = (const int*)d_in[5];

    char* ws = (char*)d_ws;
    u64*   Bmask  = (u64*)(ws + OFF_BMASK);
    u64*   cmask  = (u64*)(ws + OFF_CMASK);
    int*   labelY = (int*)(ws + OFF_LABELY);
    int*   ovr    = (int*)(ws + OFF_OVR);
    int*   ylab   = (int*)(ws + OFF_YLAB);
    int*   ccount = (int*)(ws + OFF_CCOUNT);
    float* A_f    = (float*)(ws + OFF_AF);
    float* RHS_f  = (float*)(ws + OFF_RHS);
    float* W      = (float*)(ws + OFF_W);
    float* WT     = (float*)(ws + OFF_WT);
    float* G      = (float*)(ws + OFF_G);
    int*   pA     = (int*)(ws + OFF_PA);
    int*   pB     = (int*)(ws + OFF_PB);
    float* rowabs = (float*)(ws + OFF_ROWABS);
    int*   scnt   = (int*)(ws + OFF_SCNT);
    int*   slist  = (int*)(ws + OFF_SLIST);
    u64*   sold   = (u64*)(ws + OFF_SOLD);
    float* likp   = (float*)(ws + OFF_PA);   /* pA is dead after last k_reduce */

    hipMemsetAsync(ovr, 0, NTRAIN * sizeof(int), stream);

    k_scatter<<<1, 128, 0, stream>>>(y, ind, ovr, ylab, ccount);
    k_prep   <<<NBLK, 256, 0, stream>>>(Y, B, ovr, ylab, labelY, Bmask, cmask, ccount);

    for (int pass = 0; pass < 3; ++pass) {
        k_bbt4   <<<NCHUNK, 256, 0, stream>>>(Bmask, cmask, pA, pB);
        k_reduce <<<41, 256, 0, stream>>>(pA, pB, ccount, A_f, RHS_f);
        k_wsolve <<<25, 256, 0, stream>>>(A_f, RHS_f, W, WT);
        k_gram   <<<16, 256, 0, stream>>>(WT, G, rowabs, scnt);
        k_fast   <<<NBLK, 256, 0, stream>>>(U, u, labelY, ovr, WT, rowabs,
                                            Bmask, slist, sold, scnt);
        k_slow   <<<1, 1024, 0, stream>>>(slist, sold, scnt, labelY, ovr,
                                          G, WT, U, u, Bmask);
    }

    k_lik  <<<NLIKB, 256, 0, stream>>>(U, u, labelY, ovr, ylab, likp);
    k_clfin<<<1, 256, 0, stream>>>(W, Bmask, ind, y, likp, (float*)d_out);
}

// Round 19
// 315.717 us; speedup vs baseline: 1.1297x; 1.1297x over previous
//
#include <hip/hip_runtime.h>
#include <hip/hip_bf16.h>

#define NTRAIN 100000
#define NBIT   64
#define NCLASS 100
#define NBATCH 128
#define NW     1563   /* ceil(100000/64) */
#define NWP    1568   /* padded stride   */
#define NP1    100001.0f
#define ETA_MU 55.0f

#define NBLK   391    /* ceil(100000/256) */
#define NLIKB  1563   /* ceil(100032/64): one block per 64 j-columns */
#define CCH    16     /* words per k_bbt4 chunk */
#define NCHUNK 98     /* 98*16 = 1568 >= NW */
#define SCAP   4096   /* slow-column list capacity */
#define SLACK  2e-5f  /* fp-rounding guard on the |p| > rowabs test */

typedef unsigned long long u64;
typedef unsigned int u32;
typedef __attribute__((ext_vector_type(8))) short bf16x8;
typedef __attribute__((ext_vector_type(4))) float f32x4;

// ---------------- workspace layout (bytes) ----------------
#define OFF_BMASK   0u                       /* u64[100000]        800000 */
#define OFF_CMASK   800000u                  /* u64[100][1568]    1254400 */
#define OFF_LABELY  2054400u                 /* int[100000]        400000 */
#define OFF_OVR     2454400u                 /* int[100000]        400000 */
#define OFF_YLAB    2854400u                 /* int[128]              512 */
#define OFF_CCOUNT  2854912u                 /* int[100]              512 */
#define OFF_AF      2855424u                 /* f32[4096]           16384 */
#define OFF_RHS     2871808u                 /* f32[100][64]        25600 */
#define OFF_W       2897408u                 /* f32[64][100]        25600 */
#define OFF_WT      2923008u                 /* f32[100][64]        25600 */
#define OFF_G       2948608u                 /* f32[64][64]         16384 */
#define OFF_PA      2967040u                 /* int[98][4096]; reused as k_likm partials f32[1563] */
#define OFF_PB      4572672u                 /* int[98][6400]     2508800 */
#define OFF_ROWABS  7081472u                 /* f32[64]               256 */
#define OFF_SCNT    7081728u                 /* int[1] (+pad)         256 */
#define OFF_SLIST   7081984u                 /* int[4096]           16384 */
#define OFF_SOLD    7098368u                 /* u64[4096]           32768 */
/* total ~7.13 MB */

__device__ __forceinline__ float blk_reduce_sum(float v, float* sbuf) {
    int tid = threadIdx.x;
    for (int off = 32; off > 0; off >>= 1) v += __shfl_down(v, off, 64);
    __syncthreads();
    if ((tid & 63) == 0) sbuf[tid >> 6] = v;
    __syncthreads();
    float t = 0.f;
    if (tid == 0) {
        int nw = (int)(blockDim.x >> 6);
        for (int q = 0; q < nw; ++q) t += sbuf[q];
    }
    return t;   // valid on tid 0 only
}

__device__ __forceinline__ short f2bf(float v) {
    __hip_bfloat16 h = __float2bfloat16(v);
    return *reinterpret_cast<short*>(&h);
}

// batch labels + override table (runs FIRST); also zeroes ccount for k_prep
__global__ void k_scatter(const float* __restrict__ y, const int* __restrict__ ind,
                          int* __restrict__ ovr, int* __restrict__ ylab,
                          int* __restrict__ ccount) {
    __shared__ int cls[NBATCH], idx[NBATCH];
    int k = threadIdx.x;
    if (k < NCLASS) ccount[k] = 0;
    if (k < NBATCH) {
        int c = 0;
        for (int r = 0; r < NCLASS; ++r)
            if (y[k * NCLASS + r] > 0.5f) c = r;
        cls[k] = c; idx[k] = ind[k]; ylab[k] = c;
    }
    __syncthreads();
    if (k == 0) {
        for (int q = 0; q < NBATCH; ++q) ovr[idx[q]] = q + 1;
    }
}

// fused: label per column (Y or override), B sign-mask, cmask via wave ballots,
// class counts via LDS histogram + deterministic integer atomics
__global__ __launch_bounds__(256) void k_prep(const float* __restrict__ Y,
                                              const float* __restrict__ B,
                                              const int* __restrict__ ovr,
                                              const int* __restrict__ ylab,
                                              int* __restrict__ labelY,
                                              u64* __restrict__ Bmask,
                                              u64* __restrict__ cmask,
                                              int* __restrict__ ccount) {
    __shared__ int hist[NCLASS];
    int tid = threadIdx.x, lane = tid & 63, wid = tid >> 6;
    if (tid < NCLASS) hist[tid] = 0;
    __syncthreads();
    int w = blockIdx.x * 4 + wid;
    int j = w * 64 + lane;
    int lab = -1;
    if (j < NTRAIN) {
        lab = 0;
        for (int r = 0; r < NCLASS; ++r)
            if (Y[r * NTRAIN + j] > 0.5f) lab = r;
        int ov = ovr[j];
        if (ov) lab = ylab[ov - 1];
        labelY[j] = lab;
        u64 m = 0ull;
        #pragma unroll
        for (int i = 0; i < NBIT; ++i)
            if (B[i * NTRAIN + j] > 0.0f) m |= (1ull << i);
        Bmask[j] = m;
        atomicAdd(&hist[lab], 1);
    }
    u64 keep0 = 0ull, keep1 = 0ull;
    for (int c = 0; c < NCLASS; ++c) {
        u64 bal = __ballot(lab == c);
        if (lane == c)      keep0 = bal;
        if (lane == c - 64) keep1 = bal;
    }
    if (w < NW) {
        cmask[(size_t)lane * NWP + w] = keep0;
        if (lane < NCLASS - 64) cmask[(size_t)(lane + 64) * NWP + w] = keep1;
    }
    __syncthreads();
    if (tid < NCLASS && hist[tid]) atomicAdd(&ccount[tid], hist[tid]);
}

// fused ballot-transpose + chunked BB^T / BY^T -> PLAIN partial stores
__global__ __launch_bounds__(256) void k_bbt4(const u64* __restrict__ Bmask,
                                              const u64* __restrict__ cmask,
                                              int* __restrict__ pA,
                                              int* __restrict__ pB) {
    __shared__ u64 Lp[64 * 17];
    __shared__ u64 Lc[100 * 17];
    int tid = threadIdx.x, lane = tid & 63, wid = tid >> 6;
    int w0 = blockIdx.x * CCH;
    for (int idx = tid; idx < 100 * CCH; idx += 256) {
        int r = idx >> 4, w = idx & 15;
        int gw = w0 + w;
        Lc[r * 17 + w] = (gw < NW) ? cmask[(size_t)r * NWP + gw] : 0ull;
    }
    for (int rr = 0; rr < 4; ++rr) {
        int w = wid * 4 + rr;
        int j = (w0 + w) * 64 + lane;
        u64 m = (j < NTRAIN) ? Bmask[j] : 0ull;
        u64 acc = 0ull;
        #pragma unroll
        for (int i = 0; i < 64; ++i) {
            u64 bal = __ballot((m >> i) & 1ull);
            if (lane == i) acc = bal;
        }
        Lp[lane * 17 + w] = acc;
    }
    __syncthreads();
    int k = lane, grp = wid;
    int cntA[16], cntB[25];
    #pragma unroll
    for (int i = 0; i < 16; ++i) cntA[i] = 0;
    #pragma unroll
    for (int i = 0; i < 25; ++i) cntB[i] = 0;
    for (int w = 0; w < CCH; ++w) {
        u64 pkw = Lp[k * 17 + w];
        #pragma unroll
        for (int li = 0; li < 16; ++li)
            cntA[li] += __popcll(pkw ^ Lp[(grp + 4 * li) * 17 + w]);
        #pragma unroll
        for (int ci = 0; ci < 25; ++ci)
            cntB[ci] += __popcll(pkw & Lc[(grp * 25 + ci) * 17 + w]);
    }
    size_t bA = (size_t)blockIdx.x * 4096;
    size_t bB = (size_t)blockIdx.x * 6400;
    #pragma unroll
    for (int li = 0; li < 16; ++li)
        pA[bA + (size_t)(grp + 4 * li) * 64 + k] = cntA[li];
    #pragma unroll
    for (int ci = 0; ci < 25; ++ci)
        pB[bB + (size_t)(grp * 25 + ci) * 64 + k] = cntB[ci];
}

// reduce partials -> A_f (scaled, zero-diag) and RHS_f[c*64+k]
__global__ __launch_bounds__(256) void k_reduce(const int* __restrict__ pA,
                                                const int* __restrict__ pB,
                                                const int* __restrict__ ccount,
                                                float* __restrict__ A_f,
                                                float* __restrict__ RHS_f) {
    int tid = threadIdx.x, blk = blockIdx.x;
    if (blk < 16) {
        int e = blk * 256 + tid;
        int s = 0;
        for (int ch = 0; ch < NCHUNK; ++ch) s += pA[(size_t)ch * 4096 + e];
        A_f[e] = ((e >> 6) == (e & 63)) ? 0.0f
                                        : (float)(NTRAIN - 2 * s) * (1.0f / NP1);
    } else {
        int e = (blk - 16) * 256 + tid;
        int s = 0;
        for (int ch = 0; ch < NCHUNK; ++ch) s += pB[(size_t)ch * 6400 + e];
        RHS_f[e] = (float)(2 * s - ccount[e >> 6]);
    }
}

// per-column Neumann solve: x <- v - A x (4 matvecs, ||A||~0.05)
__global__ __launch_bounds__(256) void k_wsolve(const float* __restrict__ A_f,
                                                const float* __restrict__ RHS_f,
                                                float* __restrict__ W_g,
                                                float* __restrict__ WT_g) {
    __shared__ float As[64 * 65];
    __shared__ float xb[4][64];
    int tid = threadIdx.x, lane = tid & 63, wid = tid >> 6;
    for (int e = tid; e < 4096; e += 256)
        As[(e >> 6) * 65 + (e & 63)] = A_f[e];
    int c = blockIdx.x * 4 + wid;
    float v = RHS_f[c * 64 + lane];
    float x = v;
    __syncthreads();
    for (int it = 0; it < 4; ++it) {
        xb[wid][lane] = x;
        __syncthreads();
        const float* __restrict__ Ar = As + lane * 65;
        const float* __restrict__ xv = xb[wid];
        float a0 = 0, a1 = 0, a2 = 0, a3 = 0;
        #pragma unroll 8
        for (int k = 0; k < 64; k += 4) {
            a0 = fmaf(Ar[k],     xv[k],     a0);
            a1 = fmaf(Ar[k + 1], xv[k + 1], a1);
            a2 = fmaf(Ar[k + 2], xv[k + 2], a2);
            a3 = fmaf(Ar[k + 3], xv[k + 3], a3);
        }
        x = v - ((a0 + a1) + (a2 + a3));
        __syncthreads();
    }
    float w = x * (1.0f / NP1);
    W_g[lane * 100 + c] = w;
    WT_g[c * 64 + lane] = w;
}

// G = W W^T (zero diag) + rowabs_i = sum_k |G[i][k]| ; zeroes slow-count
__global__ __launch_bounds__(256) void k_gram(const float* __restrict__ WT,
                                              float* __restrict__ G_g,
                                              float* __restrict__ rowabs,
                                              int* __restrict__ scnt) {
    __shared__ float WTs[6400];
    int tid = threadIdx.x;
    for (int e = tid; e < 6400; e += 256) WTs[e] = WT[e];
    __syncthreads();
    int e = blockIdx.x * 256 + tid;
    int k = e >> 6, l = e & 63;
    float a0 = 0, a1 = 0;
    #pragma unroll 10
    for (int c = 0; c < 100; c += 2) {
        a0 = fmaf(WTs[c * 64 + k],       WTs[c * 64 + l],       a0);
        a1 = fmaf(WTs[(c + 1) * 64 + k], WTs[(c + 1) * 64 + l], a1);
    }
    float g = (k == l) ? 0.0f : (a0 + a1);
    G_g[e] = g;
    float v = fabsf(g);
    for (int off = 32; off > 0; off >>= 1) v += __shfl_down(v, off, 64);
    if ((tid & 63) == 0) rowabs[k] = v;
    if (blockIdx.x == 0 && tid == 0) *scnt = 0;
}

// ---------------- fast scan: B = sign(p), flag |p|<=rowabs columns ----------------
// EXACT for unflagged columns: |f_i| <= rowabs_i < |p_i| for every step of the
// reference's sequential scan => sign(p_i - f_i) == sign(p_i) regardless of state.
__global__ __launch_bounds__(256) void k_fast(const float* __restrict__ U,
                                              const float* __restrict__ u,
                                              const int* __restrict__ labelY,
                                              const int* __restrict__ ovr,
                                              const float* __restrict__ WT,
                                              const float* __restrict__ rowabs,
                                              u64* __restrict__ Bmask,
                                              int* __restrict__ slist,
                                              u64* __restrict__ sold,
                                              int* __restrict__ scnt) {
    __shared__ float WTs[100 * 65];   /* 65-pad: lane-varying c -> conflict-free */
    __shared__ float ra[64];
    int tid = threadIdx.x;
    for (int e = tid; e < 6400; e += 256)
        WTs[(e >> 6) * 65 + (e & 63)] = WT[e];
    if (tid < 64) ra[tid] = rowabs[tid] + SLACK;
    __syncthreads();
    int j = blockIdx.x * 256 + tid;
    if (j >= NTRAIN) return;
    int c = labelY[j], ov = ovr[j];
    const float* up; int str;
    if (ov) { up = u + (ov - 1) * NBIT; str = 1; }
    else    { up = U + j;               str = NTRAIN; }
    const float* wc = WTs + c * 65;
    u64 m = 0ull;
    int slow = 0;
    #pragma unroll
    for (int i = 0; i < NBIT; ++i) {
        float p = fmaf(ETA_MU, up[i * str], wc[i]);
        if (p > 0.0f) m |= (1ull << i);
        slow |= (fabsf(p) <= ra[i]);
    }
    if (slow) {
        int idx = atomicAdd(scnt, 1);
        if (idx < SCAP) { slist[idx] = j; sold[idx] = Bmask[j]; }
    }
    Bmask[j] = m;   // fallback for (impossible) list overflow; exact otherwise
}

// ---------------- wave-cooperative exact scan for flagged columns -------------
__global__ __launch_bounds__(1024) void k_slow(const int* __restrict__ slist,
                                               const u64* __restrict__ sold,
                                               const int* __restrict__ scnt,
                                               const int* __restrict__ labelY,
                                               const int* __restrict__ ovr,
                                               const float* __restrict__ G_g,
                                               const float* __restrict__ WT,
                                               const float* __restrict__ U,
                                               const float* __restrict__ u,
                                               u64* __restrict__ Bmask) {
    __shared__ float Gs[64 * 65];
    int tid = threadIdx.x, lane = tid & 63, wv = tid >> 6;   /* 16 waves */
    int n = *scnt; if (n > SCAP) n = SCAP;
    if (n == 0) return;
    for (int e = tid; e < 4096; e += 1024)
        Gs[(e >> 6) * 65 + (e & 63)] = G_g[e];
    __syncthreads();
    for (int idx = wv; idx < n; idx += 16) {
        int j = slist[idx];
        u64 m0 = sold[idx];
        int c = labelY[j], ov = ovr[j];
        float uval = ov ? u[(ov - 1) * NBIT + lane]
                        : U[(size_t)lane * NTRAIN + j];
        float p = fmaf(ETA_MU, uval, WT[c * 64 + lane]);
        float s = ((m0 >> lane) & 1ull) ? 1.0f : -1.0f;
        for (int i = 0; i < 64; ++i) {
            float t = Gs[i * 65 + lane] * s;   /* G[i,i]=0 -> self term drops */
            t += __shfl_xor(t, 1);  t += __shfl_xor(t, 2);
            t += __shfl_xor(t, 4);  t += __shfl_xor(t, 8);
            t += __shfl_xor(t, 16); t += __shfl_xor(t, 32);
            float nv = ((p - t) > 0.0f) ? 1.0f : -1.0f;
            s = (lane == i) ? nv : s;
        }
        u64 mo = __ballot(s > 0.0f);
        if (lane == 0) Bmask[j] = mo;
    }
}

// ---------------- likelihood via MFMA (the dot-product IS a GEMM) -------------
// ip[128 x 100000] = u[128x64] @ Ucol[64x100000], tiled 16x16 per wave with
// mfma_f32_16x16x32_bf16 (2 MFMA per tile over K=64). r12-r18 lesson: the
// scalar-FMA form is issue-bound at ~7000 instr/wave; MFMA needs ~300.
// bf16 rounding error on the final MEAN is ~1e-4 << 3.5e-2 threshold.
// Layouts (guide-verified C/D; standard A/B for gfx950):
//   A[m][k]: m=lane&15, k=(lane>>4)*8+i  (u tile from LDS, pad 72)
//   B[k][n]: n=lane&15, k=(lane>>4)*8+i  (U column-gather, built once/wave)
//   D:       n=lane&15, m=(lane>>4)*4+r
__global__ __launch_bounds__(256) void k_likm(const float* __restrict__ U,
                                              const float* __restrict__ u,
                                              const int* __restrict__ labelY,
                                              const int* __restrict__ ovr,
                                              const int* __restrict__ ylab,
                                              float* __restrict__ partials) {
    __shared__ short ubf[128 * 72];
    __shared__ int ylab_s[NBATCH];
    __shared__ float sbuf[8];
    int tid = threadIdx.x;
    for (int e = tid; e < NBATCH * NBIT; e += 256)
        ubf[(e >> 6) * 72 + (e & 63)] = f2bf(u[e]);
    if (tid < NBATCH) ylab_s[tid] = ylab[tid];
    __syncthreads();
    int w = tid >> 6, lane = tid & 63;
    int g = lane >> 4, c = lane & 15;
    int j = blockIdx.x * 64 + w * 16 + c;
    int jl = (j < NTRAIN) ? j : (NTRAIN - 1);
    int ov = ovr[jl];
    int lab = labelY[jl];
    const float* colp; int cstr;
    if (ov) { colp = u + (ov - 1) * NBIT; cstr = 1; }
    else    { colp = U + jl;              cstr = NTRAIN; }
    bf16x8 bf0, bf1;
    #pragma unroll
    for (int i = 0; i < 8; ++i) {
        bf0[i] = f2bf(colp[(g * 8 + i) * cstr]);
        bf1[i] = f2bf(colp[(32 + g * 8 + i) * cstr]);
    }
    float acc = 0.0f;
    #pragma unroll
    for (int bt = 0; bt < 8; ++bt) {
        bf16x8 a0 = *reinterpret_cast<const bf16x8*>(&ubf[(bt * 16 + c) * 72 + g * 8]);
        bf16x8 a1 = *reinterpret_cast<const bf16x8*>(&ubf[(bt * 16 + c) * 72 + 32 + g * 8]);
        f32x4 d = {0.f, 0.f, 0.f, 0.f};
        d = __builtin_amdgcn_mfma_f32_16x16x32_bf16(a0, bf0, d, 0, 0, 0);
        d = __builtin_amdgcn_mfma_f32_16x16x32_bf16(a1, bf1, d, 0, 0, 0);
        #pragma unroll
        for (int r = 0; r < 4; ++r) {
            int b = bt * 16 + g * 4 + r;
            float ipv = 0.5f * d[r];
            float aip = fabsf(ipv);
            float t = __logf(1.0f + __expf(-aip)) + fmaxf(ipv, 0.0f);
            if (ylab_s[b] == lab) t -= ipv;
            acc += t;
        }
    }
    if (j >= NTRAIN) acc = 0.0f;
    float tot = blk_reduce_sum(acc, sbuf);
    if (tid == 0) partials[blockIdx.x] = tot;
}

// fused: cl/reg losses + final combine
__global__ void k_clfin(const float* __restrict__ Wg,
                        const u64* __restrict__ Bmask,
                        const int* __restrict__ ind,
                        const float* __restrict__ y,
                        const float* __restrict__ partials,
                        float* __restrict__ out) {
    __shared__ float sbuf[8];
    __shared__ u64 mB[NBATCH];
    int tid = threadIdx.x;
    if (tid < NBATCH) mB[tid] = Bmask[ind[tid]];
    __syncthreads();
    float accCl = 0.f;
    for (int e = tid; e < NCLASS * NBATCH; e += 256) {
        int b = e & 127, c = e >> 7;
        u64 m = mB[b];
        float d0 = 0.f;
        #pragma unroll
        for (int i = 0; i < NBIT; ++i) {
            float w = Wg[i * NCLASS + c];
            d0 += ((m >> i) & 1ull) ? w : -w;
        }
        float diff = y[b * NCLASS + c] - d0;
        accCl = fmaf(diff, diff, accCl);
    }
    float accRg = 0.f;
    for (int e = tid; e < NBIT * NCLASS; e += 256) {
        float w = Wg[e];
        accRg = fmaf(w, w, accRg);
    }
    float a = 0.f;
    for (int i = tid; i < NLIKB; i += 256) a += partials[i];
    float clS  = blk_reduce_sum(accCl, sbuf);
    float rgS  = blk_reduce_sum(accRg, sbuf);
    float lik  = blk_reduce_sum(a, sbuf);
    if (tid == 0) {
        out[0] = lik * (1.0f / ((float)NBATCH * (float)NTRAIN))
               + clS * (1.0f / (float)(NCLASS * NBATCH))
               + rgS * (1.0f / (float)(NBIT * NCLASS));
    }
}

extern "C" void kernel_launch(void* const* d_in, const int* in_sizes, int n_in,
                              void* d_out, int out_size, void* d_ws, size_t ws_size,
                              hipStream_t stream) {
    const float* u   = (const float*)d_in[0];
    const float* y   = (const float*)d_in[1];
    const float* U   = (const float*)d_in[2];
    const float* B   = (const float*)d_in[3];
    const float* Y   = (const float*)d_in[4];
    const int*   ind = (const int*)d_in[5];

    char* ws = (char*)d_ws;
    u64*   Bmask  = (u64*)(ws + OFF_BMASK);
    u64*   cmask  = (u64*)(ws + OFF_CMASK);
    int*   labelY = (int*)(ws + OFF_LABELY);
    int*   ovr    = (int*)(ws + OFF_OVR);
    int*   ylab   = (int*)(ws + OFF_YLAB);
    int*   ccount = (int*)(ws + OFF_CCOUNT);
    float* A_f    = (float*)(ws + OFF_AF);
    float* RHS_f  = (float*)(ws + OFF_RHS);
    float* W      = (float*)(ws + OFF_W);
    float* WT     = (float*)(ws + OFF_WT);
    float* G      = (float*)(ws + OFF_G);
    int*   pA     = (int*)(ws + OFF_PA);
    int*   pB     = (int*)(ws + OFF_PB);
    float* rowabs = (float*)(ws + OFF_ROWABS);
    int*   scnt   = (int*)(ws + OFF_SCNT);
    int*   slist  = (int*)(ws + OFF_SLIST);
    u64*   sold   = (u64*)(ws + OFF_SOLD);
    float* likp   = (float*)(ws + OFF_PA);   /* pA is dead after last k_reduce */

    hipMemsetAsync(ovr, 0, NTRAIN * sizeof(int), stream);

    k_scatter<<<1, 128, 0, stream>>>(y, ind, ovr, ylab, ccount);
    k_prep   <<<NBLK, 256, 0, stream>>>(Y, B, ovr, ylab, labelY, Bmask, cmask, ccount);

    for (int pass = 0; pass < 3; ++pass) {
        k_bbt4   <<<NCHUNK, 256, 0, stream>>>(Bmask, cmask, pA, pB);
        k_reduce <<<41, 256, 0, stream>>>(pA, pB, ccount, A_f, RHS_f);
        k_wsolve <<<25, 256, 0, stream>>>(A_f, RHS_f, W, WT);
        k_gram   <<<16, 256, 0, stream>>>(WT, G, rowabs, scnt);
        k_fast   <<<NBLK, 256, 0, stream>>>(U, u, labelY, ovr, WT, rowabs,
                                            Bmask, slist, sold, scnt);
        k_slow   <<<1, 1024, 0, stream>>>(slist, sold, scnt, labelY, ovr,
                                          G, WT, U, u, Bmask);
    }

    k_likm <<<NLIKB, 256, 0, stream>>>(U, u, labelY, ovr, ylab, likp);
    k_clfin<<<1, 256, 0, stream>>>(W, Bmask, ind, y, likp, (float*)d_out);
}

// Round 20
// 270.560 us; speedup vs baseline: 1.3183x; 1.1669x over previous
//
#include <hip/hip_runtime.h>
#include <hip/hip_bf16.h>

#define NTRAIN 100000
#define NBIT   64
#define NCLASS 100
#define NBATCH 128
#define NW     1563   /* ceil(100000/64) */
#define NWP    1568   /* padded stride   */
#define NP1    100001.0f
#define ETA_MU 55.0f

#define NBLK   391    /* ceil(100000/256) */
#define NLIKB  1563   /* ceil(100032/64): one block per 64 j-columns */
#define NCLB   50     /* 50*256 = 12800 = NCLASS*NBATCH */
#define CCH    16     /* words per k_bbt4 chunk */
#define NCHUNK 98     /* 98*16 = 1568 >= NW */
#define SCAP   4096   /* slow-column list capacity */
#define SLACK  2e-5f  /* fp-rounding guard on the |p| > rowabs test */

typedef unsigned long long u64;
typedef unsigned int u32;
typedef __attribute__((ext_vector_type(8))) short bf16x8;
typedef __attribute__((ext_vector_type(4))) float f32x4;

// ---------------- workspace layout (bytes) ----------------
#define OFF_BMASK   0u                       /* u64[100000]        800000 */
#define OFF_CMASK   800000u                  /* u64[100][1568]    1254400 */
#define OFF_LABELY  2054400u                 /* int[100000]        400000 */
#define OFF_OVR     2454400u                 /* int[100000]        400000 */
#define OFF_YLAB    2854400u                 /* int[128]              512 */
#define OFF_CCOUNT  2854912u                 /* int[100]              512 */
#define OFF_AF      2855424u                 /* f32[4096]           16384 */
#define OFF_RHS     2871808u                 /* f32[100][64]        25600 */
#define OFF_W       2897408u                 /* f32[64][100]        25600 */
#define OFF_WT      2923008u                 /* f32[100][64]        25600 */
#define OFF_G       2948608u                 /* f32[64][64]         16384 */
#define OFF_PA      2967040u                 /* int[98][4096]; reused: likp f32[1563] */
#define OFF_CLP     2975232u                 /* (inside pA region) clp f32[50] */
#define OFF_PB      4572672u                 /* int[98][6400]     2508800 */
#define OFF_ROWABS  7081472u                 /* f32[64]               256 */
#define OFF_SCNT    7081728u                 /* int[1] (+pad)         256 */
#define OFF_SLIST   7081984u                 /* int[4096]           16384 */
#define OFF_SOLD    7098368u                 /* u64[4096]           32768 */
/* total ~7.13 MB */

__device__ __forceinline__ float blk_reduce_sum(float v, float* sbuf) {
    int tid = threadIdx.x;
    for (int off = 32; off > 0; off >>= 1) v += __shfl_down(v, off, 64);
    __syncthreads();
    if ((tid & 63) == 0) sbuf[tid >> 6] = v;
    __syncthreads();
    float t = 0.f;
    if (tid == 0) {
        int nw = (int)(blockDim.x >> 6);
        for (int q = 0; q < nw; ++q) t += sbuf[q];
    }
    return t;   // valid on tid 0 only
}

__device__ __forceinline__ short f2bf(float v) {
    __hip_bfloat16 h = __float2bfloat16(v);
    return *reinterpret_cast<short*>(&h);
}

// batch labels + override table (runs FIRST); also zeroes ccount for k_prep
__global__ void k_scatter(const float* __restrict__ y, const int* __restrict__ ind,
                          int* __restrict__ ovr, int* __restrict__ ylab,
                          int* __restrict__ ccount) {
    __shared__ int cls[NBATCH], idx[NBATCH];
    int k = threadIdx.x;
    if (k < NCLASS) ccount[k] = 0;
    if (k < NBATCH) {
        int c = 0;
        for (int r = 0; r < NCLASS; ++r)
            if (y[k * NCLASS + r] > 0.5f) c = r;
        cls[k] = c; idx[k] = ind[k]; ylab[k] = c;
    }
    __syncthreads();
    if (k == 0) {
        for (int q = 0; q < NBATCH; ++q) ovr[idx[q]] = q + 1;
    }
}

// fused: label per column (Y or override), B sign-mask, cmask via wave ballots,
// class counts via LDS histogram + deterministic integer atomics
__global__ __launch_bounds__(256) void k_prep(const float* __restrict__ Y,
                                              const float* __restrict__ B,
                                              const int* __restrict__ ovr,
                                              const int* __restrict__ ylab,
                                              int* __restrict__ labelY,
                                              u64* __restrict__ Bmask,
                                              u64* __restrict__ cmask,
                                              int* __restrict__ ccount) {
    __shared__ int hist[NCLASS];
    int tid = threadIdx.x, lane = tid & 63, wid = tid >> 6;
    if (tid < NCLASS) hist[tid] = 0;
    __syncthreads();
    int w = blockIdx.x * 4 + wid;
    int j = w * 64 + lane;
    int lab = -1;
    if (j < NTRAIN) {
        lab = 0;
        for (int r = 0; r < NCLASS; ++r)
            if (Y[r * NTRAIN + j] > 0.5f) lab = r;
        int ov = ovr[j];
        if (ov) lab = ylab[ov - 1];
        labelY[j] = lab;
        u64 m = 0ull;
        #pragma unroll
        for (int i = 0; i < NBIT; ++i)
            if (B[i * NTRAIN + j] > 0.0f) m |= (1ull << i);
        Bmask[j] = m;
        atomicAdd(&hist[lab], 1);
    }
    u64 keep0 = 0ull, keep1 = 0ull;
    for (int c = 0; c < NCLASS; ++c) {
        u64 bal = __ballot(lab == c);
        if (lane == c)      keep0 = bal;
        if (lane == c - 64) keep1 = bal;
    }
    if (w < NW) {
        cmask[(size_t)lane * NWP + w] = keep0;
        if (lane < NCLASS - 64) cmask[(size_t)(lane + 64) * NWP + w] = keep1;
    }
    __syncthreads();
    if (tid < NCLASS && hist[tid]) atomicAdd(&ccount[tid], hist[tid]);
}

// fused ballot-transpose + chunked BB^T / BY^T -> PLAIN partial stores
__global__ __launch_bounds__(256) void k_bbt4(const u64* __restrict__ Bmask,
                                              const u64* __restrict__ cmask,
                                              int* __restrict__ pA,
                                              int* __restrict__ pB) {
    __shared__ u64 Lp[64 * 17];
    __shared__ u64 Lc[100 * 17];
    int tid = threadIdx.x, lane = tid & 63, wid = tid >> 6;
    int w0 = blockIdx.x * CCH;
    for (int idx = tid; idx < 100 * CCH; idx += 256) {
        int r = idx >> 4, w = idx & 15;
        int gw = w0 + w;
        Lc[r * 17 + w] = (gw < NW) ? cmask[(size_t)r * NWP + gw] : 0ull;
    }
    for (int rr = 0; rr < 4; ++rr) {
        int w = wid * 4 + rr;
        int j = (w0 + w) * 64 + lane;
        u64 m = (j < NTRAIN) ? Bmask[j] : 0ull;
        u64 acc = 0ull;
        #pragma unroll
        for (int i = 0; i < 64; ++i) {
            u64 bal = __ballot((m >> i) & 1ull);
            if (lane == i) acc = bal;
        }
        Lp[lane * 17 + w] = acc;
    }
    __syncthreads();
    int k = lane, grp = wid;
    int cntA[16], cntB[25];
    #pragma unroll
    for (int i = 0; i < 16; ++i) cntA[i] = 0;
    #pragma unroll
    for (int i = 0; i < 25; ++i) cntB[i] = 0;
    for (int w = 0; w < CCH; ++w) {
        u64 pkw = Lp[k * 17 + w];
        #pragma unroll
        for (int li = 0; li < 16; ++li)
            cntA[li] += __popcll(pkw ^ Lp[(grp + 4 * li) * 17 + w]);
        #pragma unroll
        for (int ci = 0; ci < 25; ++ci)
            cntB[ci] += __popcll(pkw & Lc[(grp * 25 + ci) * 17 + w]);
    }
    size_t bA = (size_t)blockIdx.x * 4096;
    size_t bB = (size_t)blockIdx.x * 6400;
    #pragma unroll
    for (int li = 0; li < 16; ++li)
        pA[bA + (size_t)(grp + 4 * li) * 64 + k] = cntA[li];
    #pragma unroll
    for (int ci = 0; ci < 25; ++ci)
        pB[bB + (size_t)(grp * 25 + ci) * 64 + k] = cntB[ci];
}

// reduce partials -> A_f (scaled, zero-diag) and RHS_f[c*64+k]
__global__ __launch_bounds__(256) void k_reduce(const int* __restrict__ pA,
                                                const int* __restrict__ pB,
                                                const int* __restrict__ ccount,
                                                float* __restrict__ A_f,
                                                float* __restrict__ RHS_f) {
    int tid = threadIdx.x, blk = blockIdx.x;
    if (blk < 16) {
        int e = blk * 256 + tid;
        int s = 0;
        for (int ch = 0; ch < NCHUNK; ++ch) s += pA[(size_t)ch * 4096 + e];
        A_f[e] = ((e >> 6) == (e & 63)) ? 0.0f
                                        : (float)(NTRAIN - 2 * s) * (1.0f / NP1);
    } else {
        int e = (blk - 16) * 256 + tid;
        int s = 0;
        for (int ch = 0; ch < NCHUNK; ++ch) s += pB[(size_t)ch * 6400 + e];
        RHS_f[e] = (float)(2 * s - ccount[e >> 6]);
    }
}

// per-column Neumann solve: x <- v - A x (4 matvecs, ||A||~0.05)
__global__ __launch_bounds__(256) void k_wsolve(const float* __restrict__ A_f,
                                                const float* __restrict__ RHS_f,
                                                float* __restrict__ W_g,
                                                float* __restrict__ WT_g) {
    __shared__ float As[64 * 65];
    __shared__ float xb[4][64];
    int tid = threadIdx.x, lane = tid & 63, wid = tid >> 6;
    for (int e = tid; e < 4096; e += 256)
        As[(e >> 6) * 65 + (e & 63)] = A_f[e];
    int c = blockIdx.x * 4 + wid;
    float v = RHS_f[c * 64 + lane];
    float x = v;
    __syncthreads();
    for (int it = 0; it < 4; ++it) {
        xb[wid][lane] = x;
        __syncthreads();
        const float* __restrict__ Ar = As + lane * 65;
        const float* __restrict__ xv = xb[wid];
        float a0 = 0, a1 = 0, a2 = 0, a3 = 0;
        #pragma unroll 8
        for (int k = 0; k < 64; k += 4) {
            a0 = fmaf(Ar[k],     xv[k],     a0);
            a1 = fmaf(Ar[k + 1], xv[k + 1], a1);
            a2 = fmaf(Ar[k + 2], xv[k + 2], a2);
            a3 = fmaf(Ar[k + 3], xv[k + 3], a3);
        }
        x = v - ((a0 + a1) + (a2 + a3));
        __syncthreads();
    }
    float w = x * (1.0f / NP1);
    W_g[lane * 100 + c] = w;
    WT_g[c * 64 + lane] = w;
}

// G = W W^T (zero diag) + rowabs_i = sum_k |G[i][k]| ; zeroes slow-count
__global__ __launch_bounds__(256) void k_gram(const float* __restrict__ WT,
                                              float* __restrict__ G_g,
                                              float* __restrict__ rowabs,
                                              int* __restrict__ scnt) {
    __shared__ float WTs[6400];
    int tid = threadIdx.x;
    for (int e = tid; e < 6400; e += 256) WTs[e] = WT[e];
    __syncthreads();
    int e = blockIdx.x * 256 + tid;
    int k = e >> 6, l = e & 63;
    float a0 = 0, a1 = 0;
    #pragma unroll 10
    for (int c = 0; c < 100; c += 2) {
        a0 = fmaf(WTs[c * 64 + k],       WTs[c * 64 + l],       a0);
        a1 = fmaf(WTs[(c + 1) * 64 + k], WTs[(c + 1) * 64 + l], a1);
    }
    float g = (k == l) ? 0.0f : (a0 + a1);
    G_g[e] = g;
    float v = fabsf(g);
    for (int off = 32; off > 0; off >>= 1) v += __shfl_down(v, off, 64);
    if ((tid & 63) == 0) rowabs[k] = v;
    if (blockIdx.x == 0 && tid == 0) *scnt = 0;
}

// ---------------- fast scan: B = sign(p), flag |p|<=rowabs columns ----------------
// EXACT for unflagged columns: |f_i| <= rowabs_i < |p_i| for every step of the
// reference's sequential scan => sign(p_i - f_i) == sign(p_i) regardless of state.
__global__ __launch_bounds__(256) void k_fast(const float* __restrict__ U,
                                              const float* __restrict__ u,
                                              const int* __restrict__ labelY,
                                              const int* __restrict__ ovr,
                                              const float* __restrict__ WT,
                                              const float* __restrict__ rowabs,
                                              u64* __restrict__ Bmask,
                                              int* __restrict__ slist,
                                              u64* __restrict__ sold,
                                              int* __restrict__ scnt) {
    __shared__ float WTs[100 * 65];   /* 65-pad: lane-varying c -> conflict-free */
    __shared__ float ra[64];
    int tid = threadIdx.x;
    for (int e = tid; e < 6400; e += 256)
        WTs[(e >> 6) * 65 + (e & 63)] = WT[e];
    if (tid < 64) ra[tid] = rowabs[tid] + SLACK;
    __syncthreads();
    int j = blockIdx.x * 256 + tid;
    if (j >= NTRAIN) return;
    int c = labelY[j], ov = ovr[j];
    const float* up; int str;
    if (ov) { up = u + (ov - 1) * NBIT; str = 1; }
    else    { up = U + j;               str = NTRAIN; }
    const float* wc = WTs + c * 65;
    u64 m = 0ull;
    int slow = 0;
    #pragma unroll
    for (int i = 0; i < NBIT; ++i) {
        float p = fmaf(ETA_MU, up[i * str], wc[i]);
        if (p > 0.0f) m |= (1ull << i);
        slow |= (fabsf(p) <= ra[i]);
    }
    if (slow) {
        int idx = atomicAdd(scnt, 1);
        if (idx < SCAP) { slist[idx] = j; sold[idx] = Bmask[j]; }
    }
    Bmask[j] = m;   // fallback for (impossible) list overflow; exact otherwise
}

// ---------------- wave-cooperative exact scan for flagged columns -------------
__global__ __launch_bounds__(1024) void k_slow(const int* __restrict__ slist,
                                               const u64* __restrict__ sold,
                                               const int* __restrict__ scnt,
                                               const int* __restrict__ labelY,
                                               const int* __restrict__ ovr,
                                               const float* __restrict__ G_g,
                                               const float* __restrict__ WT,
                                               const float* __restrict__ U,
                                               const float* __restrict__ u,
                                               u64* __restrict__ Bmask) {
    __shared__ float Gs[64 * 65];
    int tid = threadIdx.x, lane = tid & 63, wv = tid >> 6;   /* 16 waves */
    int n = *scnt; if (n > SCAP) n = SCAP;
    if (n == 0) return;
    for (int e = tid; e < 4096; e += 1024)
        Gs[(e >> 6) * 65 + (e & 63)] = G_g[e];
    __syncthreads();
    for (int idx = wv; idx < n; idx += 16) {
        int j = slist[idx];
        u64 m0 = sold[idx];
        int c = labelY[j], ov = ovr[j];
        float uval = ov ? u[(ov - 1) * NBIT + lane]
                        : U[(size_t)lane * NTRAIN + j];
        float p = fmaf(ETA_MU, uval, WT[c * 64 + lane]);
        float s = ((m0 >> lane) & 1ull) ? 1.0f : -1.0f;
        for (int i = 0; i < 64; ++i) {
            float t = Gs[i * 65 + lane] * s;   /* G[i,i]=0 -> self term drops */
            t += __shfl_xor(t, 1);  t += __shfl_xor(t, 2);
            t += __shfl_xor(t, 4);  t += __shfl_xor(t, 8);
            t += __shfl_xor(t, 16); t += __shfl_xor(t, 32);
            float nv = ((p - t) > 0.0f) ? 1.0f : -1.0f;
            s = (lane == i) ? nv : s;
        }
        u64 mo = __ballot(s > 0.0f);
        if (lane == 0) Bmask[j] = mo;
    }
}

// ---------------- likelihood via MFMA (the dot-product IS a GEMM) -------------
__global__ __launch_bounds__(256) void k_likm(const float* __restrict__ U,
                                              const float* __restrict__ u,
                                              const int* __restrict__ labelY,
                                              const int* __restrict__ ovr,
                                              const int* __restrict__ ylab,
                                              float* __restrict__ partials) {
    __shared__ short ubf[128 * 72];
    __shared__ int ylab_s[NBATCH];
    __shared__ float sbuf[8];
    int tid = threadIdx.x;
    for (int e = tid; e < NBATCH * NBIT; e += 256)
        ubf[(e >> 6) * 72 + (e & 63)] = f2bf(u[e]);
    if (tid < NBATCH) ylab_s[tid] = ylab[tid];
    __syncthreads();
    int w = tid >> 6, lane = tid & 63;
    int g = lane >> 4, c = lane & 15;
    int j = blockIdx.x * 64 + w * 16 + c;
    int jl = (j < NTRAIN) ? j : (NTRAIN - 1);
    int ov = ovr[jl];
    int lab = labelY[jl];
    const float* colp; int cstr;
    if (ov) { colp = u + (ov - 1) * NBIT; cstr = 1; }
    else    { colp = U + jl;              cstr = NTRAIN; }
    bf16x8 bf0, bf1;
    #pragma unroll
    for (int i = 0; i < 8; ++i) {
        bf0[i] = f2bf(colp[(g * 8 + i) * cstr]);
        bf1[i] = f2bf(colp[(32 + g * 8 + i) * cstr]);
    }
    float acc = 0.0f;
    #pragma unroll
    for (int bt = 0; bt < 8; ++bt) {
        bf16x8 a0 = *reinterpret_cast<const bf16x8*>(&ubf[(bt * 16 + c) * 72 + g * 8]);
        bf16x8 a1 = *reinterpret_cast<const bf16x8*>(&ubf[(bt * 16 + c) * 72 + 32 + g * 8]);
        f32x4 d = {0.f, 0.f, 0.f, 0.f};
        d = __builtin_amdgcn_mfma_f32_16x16x32_bf16(a0, bf0, d, 0, 0, 0);
        d = __builtin_amdgcn_mfma_f32_16x16x32_bf16(a1, bf1, d, 0, 0, 0);
        #pragma unroll
        for (int r = 0; r < 4; ++r) {
            int b = bt * 16 + g * 4 + r;
            float ipv = 0.5f * d[r];
            float aip = fabsf(ipv);
            float t = __logf(1.0f + __expf(-aip)) + fmaxf(ipv, 0.0f);
            if (ylab_s[b] == lab) t -= ipv;
            acc += t;
        }
    }
    if (j >= NTRAIN) acc = 0.0f;
    float tot = blk_reduce_sum(acc, sbuf);
    if (tid == 0) partials[blockIdx.x] = tot;
}

// ---------------- cl-loss, parallel: one thread per (c,b) element -------------
// r19 lesson: the fused 1-block k_clfin was a 70us straggler (3200 scattered
// stride-100 W loads per thread on one CU). 50 blocks + CONTIGUOUS WT rows
// (16 float4 per element) fixes both the parallelism and the access pattern.
__global__ __launch_bounds__(256) void k_cl(const float* __restrict__ WT,
                                            const u64* __restrict__ Bmask,
                                            const int* __restrict__ ind,
                                            const float* __restrict__ y,
                                            float* __restrict__ clp) {
    __shared__ float sbuf[8];
    __shared__ u64 mB[NBATCH];
    int tid = threadIdx.x;
    if (tid < NBATCH) mB[tid] = Bmask[ind[tid]];
    __syncthreads();
    int e = blockIdx.x * 256 + tid;       /* e < 12800 exactly */
    int b = e & 127, c = e >> 7;
    u64 m = mB[b];
    const float4* __restrict__ wr = (const float4*)(WT + c * 64);
    float d0 = 0.f, d1 = 0.f, d2 = 0.f, d3 = 0.f;
    #pragma unroll
    for (int q = 0; q < 16; ++q) {
        float4 w4 = wr[q];
        int kb = q << 2;
        d0 += ((m >> kb) & 1ull)       ? w4.x : -w4.x;
        d1 += ((m >> (kb + 1)) & 1ull) ? w4.y : -w4.y;
        d2 += ((m >> (kb + 2)) & 1ull) ? w4.z : -w4.z;
        d3 += ((m >> (kb + 3)) & 1ull) ? w4.w : -w4.w;
    }
    float d = (d0 + d1) + (d2 + d3);
    float diff = y[b * NCLASS + c] - d;
    float tot = blk_reduce_sum(diff * diff, sbuf);
    if (tid == 0) clp[blockIdx.x] = tot;
}

// ---------------- final combine: lik partials + cl partials + reg loss --------
__global__ void k_fin(const float* __restrict__ WT,
                      const float* __restrict__ likp,
                      const float* __restrict__ clp,
                      float* __restrict__ out) {
    __shared__ float sbuf[8];
    int tid = threadIdx.x;
    float a = 0.f;
    for (int i = tid; i < NLIKB; i += 256) a += likp[i];
    float cl = 0.f;
    for (int i = tid; i < NCLB; i += 256) cl += clp[i];
    float rg = 0.f;
    for (int e = tid; e < NBIT * NCLASS; e += 256) {
        float w = WT[e];
        rg = fmaf(w, w, rg);
    }
    float lik = blk_reduce_sum(a, sbuf);
    float clS = blk_reduce_sum(cl, sbuf);
    float rgS = blk_reduce_sum(rg, sbuf);
    if (tid == 0) {
        out[0] = lik * (1.0f / ((float)NBATCH * (float)NTRAIN))
               + clS * (1.0f / (float)(NCLASS * NBATCH))
               + rgS * (1.0f / (float)(NBIT * NCLASS));
    }
}

extern "C" void kernel_launch(void* const* d_in, const int* in_sizes, int n_in,
                              void* d_out, int out_size, void* d_ws, size_t ws_size,
                              hipStream_t stream) {
    const float* u   = (const float*)d_in[0];
    const float* y   = (const float*)d_in[1];
    const float* U   = (const float*)d_in[2];
    const float* B   = (const float*)d_in[3];
    const float* Y   = (const float*)d_in[4];
    const int*   ind = (const int*)d_in[5];

    char* ws = (char*)d_ws;
    u64*   Bmask  = (u64*)(ws + OFF_BMASK);
    u64*   cmask  = (u64*)(ws + OFF_CMASK);
    int*   labelY = (int*)(ws + OFF_LABELY);
    int*   ovr    = (int*)(ws + OFF_OVR);
    int*   ylab   = (int*)(ws + OFF_YLAB);
    int*   ccount = (int*)(ws + OFF_CCOUNT);
    float* A_f    = (float*)(ws + OFF_AF);
    float* RHS_f  = (float*)(ws + OFF_RHS);
    float* W      = (float*)(ws + OFF_W);
    float* WT     = (float*)(ws + OFF_WT);
    float* G      = (float*)(ws + OFF_G);
    int*   pA     = (int*)(ws + OFF_PA);
    int*   pB     = (int*)(ws + OFF_PB);
    float* rowabs = (float*)(ws + OFF_ROWABS);
    int*   scnt   = (int*)(ws + OFF_SCNT);
    int*   slist  = (int*)(ws + OFF_SLIST);
    u64*   sold   = (u64*)(ws + OFF_SOLD);
    float* likp   = (float*)(ws + OFF_PA);   /* pA region is dead after last k_reduce */
    float* clp    = (float*)(ws + OFF_CLP);

    hipMemsetAsync(ovr, 0, NTRAIN * sizeof(int), stream);

    k_scatter<<<1, 128, 0, stream>>>(y, ind, ovr, ylab, ccount);
    k_prep   <<<NBLK, 256, 0, stream>>>(Y, B, ovr, ylab, labelY, Bmask, cmask, ccount);

    for (int pass = 0; pass < 3; ++pass) {
        k_bbt4   <<<NCHUNK, 256, 0, stream>>>(Bmask, cmask, pA, pB);
        k_reduce <<<41, 256, 0, stream>>>(pA, pB, ccount, A_f, RHS_f);
        k_wsolve <<<25, 256, 0, stream>>>(A_f, RHS_f, W, WT);
        k_gram   <<<16, 256, 0, stream>>>(WT, G, rowabs, scnt);
        k_fast   <<<NBLK, 256, 0, stream>>>(U, u, labelY, ovr, WT, rowabs,
                                            Bmask, slist, sold, scnt);
        k_slow   <<<1, 1024, 0, stream>>>(slist, sold, scnt, labelY, ovr,
                                          G, WT, U, u, Bmask);
    }

    k_likm <<<NLIKB, 256, 0, stream>>>(U, u, labelY, ovr, ylab, likp);
    k_cl   <<<NCLB, 256, 0, stream>>>(WT, Bmask, ind, y, clp);
    k_fin  <<<1, 256, 0, stream>>>(WT, likp, clp, (float*)d_out);
}